// Round 6
// baseline (242.454 us; speedup 1.0000x reference)
//
#include <hip/hip_runtime.h>
#include <math.h>

#define Bn 2
#define DM 192
#define DI 384
#define DS 16
#define HH 64
#define WW 64
#define HW 4096
#define ND 4

__device__ __forceinline__ float fastrcp(float x) { return __builtin_amdgcn_rcpf(x); }
__device__ __forceinline__ float fsig(float x) {
    return fastrcp(1.0f + __expf(-x));
}

// ---------------- K1: in_proj (1x1) + SiLU ----------------
// grid (16, 24, 2), block 256.
__global__ __launch_bounds__(256, 3) void k_inproj(const float* __restrict__ x,
                                                   const float* __restrict__ w,
                                                   float* __restrict__ hpre) {
    int og = blockIdx.y, b = blockIdx.z;
    int p = blockIdx.x * 256 + threadIdx.x;
    const float* wr = w + (size_t)og * 16 * DM;
    const float* xb = x + (size_t)b * DM * HW + p;
    float acc[16];
#pragma unroll
    for (int j = 0; j < 16; ++j) acc[j] = 0.f;
    for (int c = 0; c < DM; c += 4) {
        float x0 = xb[(size_t)(c + 0) * HW];
        float x1 = xb[(size_t)(c + 1) * HW];
        float x2 = xb[(size_t)(c + 2) * HW];
        float x3 = xb[(size_t)(c + 3) * HW];
#pragma unroll
        for (int j = 0; j < 16; ++j) {
            const float* wj = wr + j * DM + c;  // wave-uniform -> SGPR
            acc[j] = fmaf(wj[0], x0, fmaf(wj[1], x1, fmaf(wj[2], x2, fmaf(wj[3], x3, acc[j]))));
        }
    }
    float* hb = hpre + (size_t)b * DI * HW + (size_t)(og * 16) * HW + p;
#pragma unroll
    for (int j = 0; j < 16; ++j) {
        float v = acc[j];
        hb[(size_t)j * HW] = v * fastrcp(1.0f + __expf(-v));
    }
}

// ---------------- K2: depthwise 3x3 conv + bias ----------------
// grid (16, 384, 2), block 256.
__global__ __launch_bounds__(256) void k_dwconv(const float* __restrict__ hpre,
                                                const float* __restrict__ w,
                                                const float* __restrict__ bias,
                                                float* __restrict__ h) {
    int c = blockIdx.y, b = blockIdx.z;
    int p = blockIdx.x * 256 + threadIdx.x;
    int i = p >> 6, j = p & 63;
    const float* wp = w + c * 9;
    const float* src = hpre + ((size_t)b * DI + c) * HW;
    float acc = bias[c];
#pragma unroll
    for (int di = -1; di <= 1; ++di) {
        int ii = i + di;
        if (ii < 0 || ii >= HH) continue;
#pragma unroll
        for (int dj = -1; dj <= 1; ++dj) {
            int jj = j + dj;
            if (jj < 0 || jj >= WW) continue;
            acc = fmaf(wp[(di + 1) * 3 + (dj + 1)], src[ii * WW + jj], acc);
        }
    }
    h[((size_t)b * DI + c) * HW + p] = acc;
}

// ---------------- K3: x_down -> xp transposed [b][p][s] ----------------
// grid (128), block 256 = 4 waves. Wave = 96-channel slice; 64 pixels/block.
__global__ __launch_bounds__(256) void k_xdown(const float* __restrict__ h,
                                               const float* __restrict__ w,
                                               float* __restrict__ xpt) {
    __shared__ float red[4][64][17];
    int tid = threadIdx.x;
    int px = tid & 63, cw = tid >> 6;
    int gp = blockIdx.x * 64 + px;
    int b = gp >> 12, p = gp & 4095;
    const float* hb = h + (size_t)b * DI * HW + p;
    int c0 = cw * 96;
    float a[16];
#pragma unroll
    for (int s = 0; s < 16; ++s) a[s] = 0.f;
    for (int cc = 0; cc < 96; cc += 4) {
        float h0 = hb[(size_t)(c0 + cc + 0) * HW];
        float h1 = hb[(size_t)(c0 + cc + 1) * HW];
        float h2 = hb[(size_t)(c0 + cc + 2) * HW];
        float h3 = hb[(size_t)(c0 + cc + 3) * HW];
#pragma unroll
        for (int s = 0; s < 16; ++s) {
            const float* ws = w + (size_t)s * DI + c0 + cc;  // wave-uniform -> s_load
            a[s] = fmaf(ws[0], h0, fmaf(ws[1], h1, fmaf(ws[2], h2, fmaf(ws[3], h3, a[s]))));
        }
    }
#pragma unroll
    for (int s = 0; s < 16; ++s) red[cw][px][s] = a[s];
    __syncthreads();
    int sg = tid >> 6;
    float4 r;
    float* o = &r.x;
#pragma unroll
    for (int j = 0; j < 4; ++j) {
        int s = sg * 4 + j;
        o[j] = red[0][px][s] + red[1][px][s] + red[2][px][s] + red[3][px][s];
    }
    *reinterpret_cast<float4*>(xpt + (size_t)gp * 16 + sg * 4) = r;
}

// 16-term dot of SGPR-resident weight array against 4 float4 quads.
#define DOT16(W, q0, q1, q2, q3) \
    fmaf(W[15], q3.w, fmaf(W[14], q3.z, fmaf(W[13], q3.y, fmaf(W[12], q3.x, \
    fmaf(W[11], q2.w, fmaf(W[10], q2.z, fmaf(W[9],  q2.y, fmaf(W[8],  q2.x, \
    fmaf(W[7],  q1.w, fmaf(W[6],  q1.z, fmaf(W[5],  q1.y, fmaf(W[4],  q1.x, \
    fmaf(W[3],  q0.w, fmaf(W[2],  q0.z, fmaf(W[1],  q0.y, W[0] * q0.x)))))))))))))))

// ---------------- K4: fused gate-recurrent scan, all 4 directions ----------------
// grid (384, 2), block 256 (4 waves = 4 directions, lane = h).
// xp staged in LDS once per block (4x dedup vs per-wave global streams, and
// coalesced 256B-segment staging loads vs 64-line gathers).
__global__ __launch_bounds__(256, 3) void k_scan(const float* __restrict__ h,
                                                 const float* __restrict__ xpt,
                                                 const float* __restrict__ wup,
                                                 const float* __restrict__ lup,
                                                 const float* __restrict__ uup,
                                                 const float* __restrict__ dup,
                                                 const float* __restrict__ mw,
                                                 float* __restrict__ y) {
    int c = blockIdx.x, b = blockIdx.y;
    int tid = threadIdx.x;
    int d = tid >> 6, hl = tid & 63;

    __shared__ float htile[64][65];
    __shared__ float acc[64][65];
    __shared__ float4 xpl[16][64];   // [w_loc*4+q][row] : 16B/lane stride -> cf b128

    const float* hb = h + ((size_t)b * DI + c) * HW;
    for (int i = tid; i < HW; i += 256) {
        htile[i >> 6][i & 63] = hb[i];
        acc[i >> 6][i & 63] = 0.f;
    }

    int row = d * DI + c;
    const float* p1 = wup + (size_t)row * DS;
    const float* p2 = wup + (size_t)(4 * DI + row) * DS;
    const float* p3 = wup + (size_t)(8 * DI + row) * DS;
    const float* pL = lup + (size_t)row * DS;
    const float* pU = uup + (size_t)row * DS;
    const float* pD = dup + (size_t)row * DS;
    float md = mw[d];
    float w1[16], w2[16], w3[16], wL[16], wU[16], wD[16];
#pragma unroll
    for (int s = 0; s < 16; ++s) {
        w1[s] = p1[s]; w2[s] = p2[s]; w3[s] = p3[s];
        wL[s] = pL[s]; wU[s] = md * pU[s]; wD[s] = md * pD[s];
    }

    int xstep = (d & 1) ? 65 : 1;
    int xbase = (d & 1) ? hl : hl * 65;
    if (d & 2) { xbase += xstep * 63; xstep = -xstep; }
    const float* xptr = &htile[0][0] + xbase;

    int upA = ((hl - 1) & 63) << 2;
    int dnA = ((hl + 1) & 63) << 2;
    bool isTop = (hl == 0), isBot = (hl == 63);

    float* accp = &acc[hl][0];

    // staging map: tid -> (srow block, w_loc, q). Global reads coalesce into
    // 4 x 256B segments per wave; LDS slot S = (w_loc*4+q)*64 + row.
    const float4* xg = reinterpret_cast<const float4*>(xpt + (size_t)b * HW * DS);
    int srow = tid >> 4, swl = (tid >> 2) & 3, sq = tid & 3;

    float4 st[4];
#pragma unroll
    for (int p = 0; p < 4; ++p) {
        int r_ = srow + 16 * p;
        st[p] = xg[(r_ * 64 + swl) * 4 + sq];
    }

    float hprev = 0.f;
    __syncthreads();  // htile + acc ready

    for (int chunk = 0; chunk < 16; ++chunk) {
#pragma unroll
        for (int p = 0; p < 4; ++p) {
            int r_ = srow + 16 * p;
            xpl[swl * 4 + sq][r_] = st[p];
        }
        __syncthreads();  // xpl ready for this chunk

        if (chunk < 15) {
            int nw0 = chunk * 4 + 4;
#pragma unroll
            for (int p = 0; p < 4; ++p) {
                int r_ = srow + 16 * p;
                st[p] = xg[(r_ * 64 + nw0 + swl) * 4 + sq];
            }
        }

#pragma unroll
        for (int j = 0; j < 4; ++j) {
            float4 q0 = xpl[j * 4 + 0][hl];
            float4 q1 = xpl[j * 4 + 1][hl];
            float4 q2 = xpl[j * 4 + 2][hl];
            float4 q3 = xpl[j * 4 + 3][hl];
            float g1 = DOT16(w1, q0, q1, q2, q3);
            float g2 = DOT16(w2, q0, q1, q2, q3);
            float g3 = DOT16(w3, q0, q1, q2, q3);
            float L  = DOT16(wL, q0, q1, q2, q3);
            float U  = DOT16(wU, q0, q1, q2, q3);
            float Dv = DOT16(wD, q0, q1, q2, q3);
            g1 = fsig(g1); g2 = fsig(g2); g3 = fsig(g3);
            float ssum = g2 + (isTop ? 0.f : g1) + (isBot ? 0.f : g3);
            float inv = fastrcp(fmaxf(ssum, 1e-7f));
            float X = *xptr; xptr += xstep;
            float up = __int_as_float(__builtin_amdgcn_ds_bpermute(upA, __float_as_int(hprev)));
            float dn = __int_as_float(__builtin_amdgcn_ds_bpermute(dnA, __float_as_int(hprev)));
            up = isTop ? 0.f : up;
            dn = isBot ? 0.f : dn;
            float hnew = fmaf(L, X, inv * fmaf(g1, up, fmaf(g2, hprev, g3 * dn)));
            hprev = hnew;
            atomicAdd(accp, fmaf(hnew, U, X * Dv));
            accp += 1;
        }
        __syncthreads();  // all waves done with xpl before overwrite
    }

    float* yb = y + ((size_t)b * DI + c) * HW;
    for (int i = tid; i < HW; i += 256) yb[i] = acc[i >> 6][i & 63];
}

// ---------------- K5: LayerNorm2d over channels, in-place, single pass ----------------
// grid (512), block 256. Block: 16 pixels x 16 channel-chunks (24 channels each).
__global__ __launch_bounds__(256) void k_ln(float* __restrict__ y,
                                            const float* __restrict__ nw,
                                            const float* __restrict__ nb) {
    int lpx = threadIdx.x & 15, chunk = threadIdx.x >> 4;
    int gp = blockIdx.x * 16 + lpx;  // global pixel 0..8191
    int b = gp >> 12, p = gp & 4095;
    float* yb = y + (size_t)b * DI * HW + p;

    float vv[24];
    float s = 0.f, s2 = 0.f;
#pragma unroll
    for (int ci = 0; ci < 24; ++ci) {
        float v = yb[(size_t)(chunk * 24 + ci) * HW];
        vv[ci] = v;
        s += v;
        s2 = fmaf(v, v, s2);
    }
    __shared__ float S[16][17], S2[16][17];
    S[chunk][lpx] = s;
    S2[chunk][lpx] = s2;
    __syncthreads();
    float ts = 0.f, ts2 = 0.f;
#pragma unroll
    for (int k = 0; k < 16; ++k) { ts += S[k][lpx]; ts2 += S2[k][lpx]; }
    float mu = ts * (1.0f / DI);
    float var = ts2 * (1.0f / DI) - mu * mu;
    float inv = rsqrtf(var + 1e-5f);
#pragma unroll
    for (int ci = 0; ci < 24; ++ci) {
        int cch = chunk * 24 + ci;
        float v = (vv[ci] - mu) * inv;
        yb[(size_t)cch * HW] = fmaf(v, nw[cch], nb[cch]);
    }
}

// ---------------- K6: GRN per-channel sumsq -> Gx = sqrt(sum y^2) ----------------
// grid (384, 2), block 256.
__global__ __launch_bounds__(256) void k_grnsum(const float* __restrict__ y,
                                                float* __restrict__ gx) {
    int c = blockIdx.x, b = blockIdx.y;
    const float* yb = y + ((size_t)b * DI + c) * HW;
    float s = 0.f;
#pragma unroll 4
    for (int i = threadIdx.x; i < HW; i += 256) {
        float v = yb[i];
        s = fmaf(v, v, s);
    }
#pragma unroll
    for (int o = 32; o > 0; o >>= 1) s += __shfl_down(s, o);
    __shared__ float red[4];
    int wid = threadIdx.x >> 6;
    if ((threadIdx.x & 63) == 0) red[wid] = s;
    __syncthreads();
    if (threadIdx.x == 0) gx[b * DI + c] = sqrtf(red[0] + red[1] + red[2] + red[3]);
}

// ---------------- K7: GRN scale: sc = 1 + gamma * Gx/(mean+1e-6) ----------------
// grid 2, block 256. Each thread covers channels cidx and cidx+256 (DI=384).
__global__ __launch_bounds__(256) void k_grnscale(const float* __restrict__ gxv,
                                                  const float* __restrict__ gamma,
                                                  float* __restrict__ sc) {
    int b = blockIdx.x;
    const float* g = gxv + b * DI;
    int cidx = threadIdx.x;
    float gx0 = g[cidx];
    float gx1 = (cidx < DI - 256) ? g[cidx + 256] : 0.f;
    float s = gx0 + gx1;
#pragma unroll
    for (int o = 32; o > 0; o >>= 1) s += __shfl_down(s, o);
    __shared__ float red[4];
    __shared__ float meanv;
    int wid = threadIdx.x >> 6;
    if ((threadIdx.x & 63) == 0) red[wid] = s;
    __syncthreads();
    if (threadIdx.x == 0) meanv = (red[0] + red[1] + red[2] + red[3]) * (1.0f / DI);
    __syncthreads();
    float m = meanv + 1e-6f;
    sc[b * DI + cidx] = 1.0f + gamma[cidx] * (gx0 / m);
    if (cidx < DI - 256)
        sc[b * DI + cidx + 256] = 1.0f + gamma[cidx + 256] * (gx1 / m);
}

// ---------------- K8: out_proj GEMM fused with GRN scale/shift ----------------
// grid (16, 24, 2), block 256. Thread: 8 output channels for one pixel.
__global__ __launch_bounds__(256, 3) void k_outproj(const float* __restrict__ y,
                                                    const float* __restrict__ w,
                                                    const float* __restrict__ sc_all,
                                                    const float* __restrict__ beta,
                                                    float* __restrict__ out) {
    int og = blockIdx.y, b = blockIdx.z;
    int p = blockIdx.x * 256 + threadIdx.x;
    const float* wr = w + (size_t)og * 8 * DI;
    const float* scb = sc_all + b * DI;
    const float* yb = y + (size_t)b * DI * HW + p;
    float acc[8];
#pragma unroll
    for (int j = 0; j < 8; ++j) acc[j] = 0.f;
    for (int c = 0; c < DI; c += 4) {
        float v0 = fmaf(yb[(size_t)(c + 0) * HW], scb[c + 0], beta[c + 0]);
        float v1 = fmaf(yb[(size_t)(c + 1) * HW], scb[c + 1], beta[c + 1]);
        float v2 = fmaf(yb[(size_t)(c + 2) * HW], scb[c + 2], beta[c + 2]);
        float v3 = fmaf(yb[(size_t)(c + 3) * HW], scb[c + 3], beta[c + 3]);
#pragma unroll
        for (int j = 0; j < 8; ++j) {
            const float* wj = wr + j * DI + c;  // wave-uniform -> SGPR
            acc[j] = fmaf(wj[0], v0, fmaf(wj[1], v1, fmaf(wj[2], v2, fmaf(wj[3], v3, acc[j]))));
        }
    }
    float* ob = out + (size_t)b * DM * HW + (size_t)(og * 8) * HW + p;
#pragma unroll
    for (int j = 0; j < 8; ++j) ob[(size_t)j * HW] = acc[j];
}

extern "C" void kernel_launch(void* const* d_in, const int* in_sizes, int n_in,
                              void* d_out, int out_size, void* d_ws, size_t ws_size,
                              hipStream_t stream) {
    (void)in_sizes; (void)n_in; (void)out_size; (void)ws_size;
    const float* x          = (const float*)d_in[0];
    const float* in_proj_w  = (const float*)d_in[1];
    const float* dwconv_w   = (const float*)d_in[2];
    const float* dwconv_b   = (const float*)d_in[3];
    const float* x_down_w   = (const float*)d_in[4];
    const float* w_up_w     = (const float*)d_in[5];
    const float* l_up_w     = (const float*)d_in[6];
    const float* u_up_w     = (const float*)d_in[7];
    const float* d_up_w     = (const float*)d_in[8];
    const float* m_w        = (const float*)d_in[9];
    const float* grn_gamma  = (const float*)d_in[10];
    const float* grn_beta   = (const float*)d_in[11];
    const float* norm_w     = (const float*)d_in[12];
    const float* norm_b     = (const float*)d_in[13];
    const float* out_proj_w = (const float*)d_in[14];

    float* ws = (float*)d_ws;
    const size_t NBIG = (size_t)Bn * DI * HW;
    float* hpre = ws;                  // [B,DI,H,W], later reused as y
    float* hbuf = ws + NBIG;           // [B,DI,H,W] post-dwconv
    float* xpt  = ws + 2 * NBIG;       // [B,HW,DS]
    float* gx   = ws + 2 * NBIG + (size_t)Bn * HW * DS;
    float* sc   = gx + Bn * DI;
    float* y    = hpre;

    k_inproj<<<dim3(16, 24, 2), 256, 0, stream>>>(x, in_proj_w, hpre);
    k_dwconv<<<dim3(16, DI, Bn), 256, 0, stream>>>(hpre, dwconv_w, dwconv_b, hbuf);
    k_xdown<<<dim3(128), 256, 0, stream>>>(hbuf, x_down_w, xpt);
    k_scan<<<dim3(DI, Bn), 256, 0, stream>>>(hbuf, xpt, w_up_w, l_up_w, u_up_w,
                                             d_up_w, m_w, y);
    k_ln<<<dim3(512), 256, 0, stream>>>(y, norm_w, norm_b);
    k_grnsum<<<dim3(DI, Bn), 256, 0, stream>>>(y, gx);
    k_grnscale<<<dim3(Bn), 256, 0, stream>>>(gx, grn_gamma, sc);
    k_outproj<<<dim3(16, 24, 2), 256, 0, stream>>>(y, out_proj_w, sc, grn_beta,
                                                   (float*)d_out);
}

// Round 7
// 224.640 us; speedup vs baseline: 1.0793x; 1.0793x over previous
//
#include <hip/hip_runtime.h>
#include <math.h>

#define Bn 2
#define DM 192
#define DI 384
#define DS 16
#define HH 64
#define WW 64
#define HW 4096
#define ND 4

__device__ __forceinline__ float fastrcp(float x) { return __builtin_amdgcn_rcpf(x); }
__device__ __forceinline__ float fsig(float x) {
    return fastrcp(1.0f + __expf(-x));
}

// ---------------- K1: in_proj (1x1) + SiLU ----------------
// grid (16, 24, 2), block 256.
__global__ __launch_bounds__(256, 3) void k_inproj(const float* __restrict__ x,
                                                   const float* __restrict__ w,
                                                   float* __restrict__ hpre) {
    int og = blockIdx.y, b = blockIdx.z;
    int p = blockIdx.x * 256 + threadIdx.x;
    const float* wr = w + (size_t)og * 16 * DM;
    const float* xb = x + (size_t)b * DM * HW + p;
    float acc[16];
#pragma unroll
    for (int j = 0; j < 16; ++j) acc[j] = 0.f;
    for (int c = 0; c < DM; c += 4) {
        float x0 = xb[(size_t)(c + 0) * HW];
        float x1 = xb[(size_t)(c + 1) * HW];
        float x2 = xb[(size_t)(c + 2) * HW];
        float x3 = xb[(size_t)(c + 3) * HW];
#pragma unroll
        for (int j = 0; j < 16; ++j) {
            const float* wj = wr + j * DM + c;  // wave-uniform -> SGPR
            acc[j] = fmaf(wj[0], x0, fmaf(wj[1], x1, fmaf(wj[2], x2, fmaf(wj[3], x3, acc[j]))));
        }
    }
    float* hb = hpre + (size_t)b * DI * HW + (size_t)(og * 16) * HW + p;
#pragma unroll
    for (int j = 0; j < 16; ++j) {
        float v = acc[j];
        hb[(size_t)j * HW] = v * fastrcp(1.0f + __expf(-v));
    }
}

// ---------------- K2: depthwise 3x3 conv + bias ----------------
// grid (16, 384, 2), block 256.
__global__ __launch_bounds__(256) void k_dwconv(const float* __restrict__ hpre,
                                                const float* __restrict__ w,
                                                const float* __restrict__ bias,
                                                float* __restrict__ h) {
    int c = blockIdx.y, b = blockIdx.z;
    int p = blockIdx.x * 256 + threadIdx.x;
    int i = p >> 6, j = p & 63;
    const float* wp = w + c * 9;
    const float* src = hpre + ((size_t)b * DI + c) * HW;
    float acc = bias[c];
#pragma unroll
    for (int di = -1; di <= 1; ++di) {
        int ii = i + di;
        if (ii < 0 || ii >= HH) continue;
#pragma unroll
        for (int dj = -1; dj <= 1; ++dj) {
            int jj = j + dj;
            if (jj < 0 || jj >= WW) continue;
            acc = fmaf(wp[(di + 1) * 3 + (dj + 1)], src[ii * WW + jj], acc);
        }
    }
    h[((size_t)b * DI + c) * HW + p] = acc;
}

// ---------------- K3: x_down -> xp transposed [b][p][s] ----------------
// grid (128), block 256 = 4 waves. Wave = 96-channel slice; 64 pixels/block.
__global__ __launch_bounds__(256) void k_xdown(const float* __restrict__ h,
                                               const float* __restrict__ w,
                                               float* __restrict__ xpt) {
    __shared__ float red[4][64][17];
    int tid = threadIdx.x;
    int px = tid & 63, cw = tid >> 6;
    int gp = blockIdx.x * 64 + px;
    int b = gp >> 12, p = gp & 4095;
    const float* hb = h + (size_t)b * DI * HW + p;
    int c0 = cw * 96;
    float a[16];
#pragma unroll
    for (int s = 0; s < 16; ++s) a[s] = 0.f;
    for (int cc = 0; cc < 96; cc += 4) {
        float h0 = hb[(size_t)(c0 + cc + 0) * HW];
        float h1 = hb[(size_t)(c0 + cc + 1) * HW];
        float h2 = hb[(size_t)(c0 + cc + 2) * HW];
        float h3 = hb[(size_t)(c0 + cc + 3) * HW];
#pragma unroll
        for (int s = 0; s < 16; ++s) {
            const float* ws = w + (size_t)s * DI + c0 + cc;  // wave-uniform -> s_load
            a[s] = fmaf(ws[0], h0, fmaf(ws[1], h1, fmaf(ws[2], h2, fmaf(ws[3], h3, a[s]))));
        }
    }
#pragma unroll
    for (int s = 0; s < 16; ++s) red[cw][px][s] = a[s];
    __syncthreads();
    int sg = tid >> 6;
    float4 r;
    float* o = &r.x;
#pragma unroll
    for (int j = 0; j < 4; ++j) {
        int s = sg * 4 + j;
        o[j] = red[0][px][s] + red[1][px][s] + red[2][px][s] + red[3][px][s];
    }
    *reinterpret_cast<float4*>(xpt + (size_t)gp * 16 + sg * 4) = r;
}

// 16-term dot of pinned-VGPR weight array against 4 float4 quads.
#define DOT16(W, q0, q1, q2, q3) \
    fmaf(W[15], q3.w, fmaf(W[14], q3.z, fmaf(W[13], q3.y, fmaf(W[12], q3.x, \
    fmaf(W[11], q2.w, fmaf(W[10], q2.z, fmaf(W[9],  q2.y, fmaf(W[8],  q2.x, \
    fmaf(W[7],  q1.w, fmaf(W[6],  q1.z, fmaf(W[5],  q1.y, fmaf(W[4],  q1.x, \
    fmaf(W[3],  q0.w, fmaf(W[2],  q0.z, fmaf(W[1],  q0.y, W[0] * q0.x)))))))))))))))

// ---------------- K4: fused gate-recurrent scan, all 4 directions ----------------
// grid (384, 2), block 256 (4 waves = 4 directions, lane = h).
// Weights are wave-uniform but not compiler-provably so; without pinning the
// compiler rematerializes them (reloads from global) inside the column loop,
// creating a ~100us VMEM floor. asm "+v" pin forces them to stay in VGPRs.
__global__ __launch_bounds__(256, 3) void k_scan(const float* __restrict__ h,
                                                 const float* __restrict__ xpt,
                                                 const float* __restrict__ wup,
                                                 const float* __restrict__ lup,
                                                 const float* __restrict__ uup,
                                                 const float* __restrict__ dup,
                                                 const float* __restrict__ mw,
                                                 float* __restrict__ y) {
    int c = blockIdx.x, b = blockIdx.y;
    int tid = threadIdx.x;
    int d = tid >> 6, hl = tid & 63;

    __shared__ float htile[64][65];
    __shared__ float acc[64][65];

    const float* hb = h + ((size_t)b * DI + c) * HW;
    for (int i = tid; i < HW; i += 256) {
        htile[i >> 6][i & 63] = hb[i];
        acc[i >> 6][i & 63] = 0.f;
    }

    int row = d * DI + c;
    const float* p1 = wup + (size_t)row * DS;
    const float* p2 = wup + (size_t)(4 * DI + row) * DS;
    const float* p3 = wup + (size_t)(8 * DI + row) * DS;
    const float* pL = lup + (size_t)row * DS;
    const float* pU = uup + (size_t)row * DS;
    const float* pD = dup + (size_t)row * DS;
    float md = mw[d];
    float w1[16], w2[16], w3[16], wL[16], wU[16], wD[16];
#pragma unroll
    for (int s = 0; s < 16; ++s) {
        w1[s] = p1[s]; w2[s] = p2[s]; w3[s] = p3[s];
        wL[s] = pL[s]; wU[s] = md * pU[s]; wD[s] = md * pD[s];
    }
    // Pin: asm def cannot be rematerialized -> values stay live in VGPRs.
#pragma unroll
    for (int s = 0; s < 16; ++s) {
        asm volatile("" : "+v"(w1[s]), "+v"(w2[s]), "+v"(w3[s]),
                          "+v"(wL[s]), "+v"(wU[s]), "+v"(wD[s]));
    }

    int xstep = (d & 1) ? 65 : 1;
    int xbase = (d & 1) ? hl : hl * 65;
    if (d & 2) { xbase += xstep * 63; xstep = -xstep; }
    const float* xptr = &htile[0][0] + xbase;

    int upA = ((hl - 1) & 63) << 2;
    int dnA = ((hl + 1) & 63) << 2;
    bool isTop = (hl == 0), isBot = (hl == 63);

    float* accp = &acc[hl][0];

    const float4* xq = reinterpret_cast<const float4*>(
        xpt + ((size_t)b * HW + (size_t)hl * 64) * DS);

    float hprev = 0.f;

    float4 A0 = xq[0], A1 = xq[1], A2 = xq[2], A3 = xq[3];
    float4 B0, B1, B2, B3;

    __syncthreads();  // htile + acc ready

    auto docol = [&](const float4& q0, const float4& q1, const float4& q2, const float4& q3) {
        float g1 = DOT16(w1, q0, q1, q2, q3);
        float g2 = DOT16(w2, q0, q1, q2, q3);
        float g3 = DOT16(w3, q0, q1, q2, q3);
        float L  = DOT16(wL, q0, q1, q2, q3);
        float U  = DOT16(wU, q0, q1, q2, q3);
        float Dv = DOT16(wD, q0, q1, q2, q3);
        g1 = fsig(g1); g2 = fsig(g2); g3 = fsig(g3);
        float ssum = g2 + (isTop ? 0.f : g1) + (isBot ? 0.f : g3);
        float inv = fastrcp(fmaxf(ssum, 1e-7f));
        float X = *xptr; xptr += xstep;
        float up = __int_as_float(__builtin_amdgcn_ds_bpermute(upA, __float_as_int(hprev)));
        float dn = __int_as_float(__builtin_amdgcn_ds_bpermute(dnA, __float_as_int(hprev)));
        up = isTop ? 0.f : up;
        dn = isBot ? 0.f : dn;
        float hnew = fmaf(L, X, inv * fmaf(g1, up, fmaf(g2, hprev, g3 * dn)));
        hprev = hnew;
        atomicAdd(accp, fmaf(hnew, U, X * Dv));
        accp += 1;
    };

    for (int w = 0; w < 64; w += 2) {
        const float4* pn = xq + (w + 1) * 4;       // col w+1
        B0 = pn[0]; B1 = pn[1]; B2 = pn[2]; B3 = pn[3];
        docol(A0, A1, A2, A3);
        int w2i = (w + 2 < 64) ? w + 2 : 63;       // clamped prefetch
        const float4* pm = xq + w2i * 4;
        A0 = pm[0]; A1 = pm[1]; A2 = pm[2]; A3 = pm[3];
        docol(B0, B1, B2, B3);
    }

    __syncthreads();
    float* yb = y + ((size_t)b * DI + c) * HW;
    for (int i = tid; i < HW; i += 256) yb[i] = acc[i >> 6][i & 63];
}

// ---------------- K5: LayerNorm2d over channels, in-place, single pass ----------------
// grid (512), block 256. Block: 16 pixels x 16 channel-chunks (24 channels each).
__global__ __launch_bounds__(256) void k_ln(float* __restrict__ y,
                                            const float* __restrict__ nw,
                                            const float* __restrict__ nb) {
    int lpx = threadIdx.x & 15, chunk = threadIdx.x >> 4;
    int gp = blockIdx.x * 16 + lpx;  // global pixel 0..8191
    int b = gp >> 12, p = gp & 4095;
    float* yb = y + (size_t)b * DI * HW + p;

    float vv[24];
    float s = 0.f, s2 = 0.f;
#pragma unroll
    for (int ci = 0; ci < 24; ++ci) {
        float v = yb[(size_t)(chunk * 24 + ci) * HW];
        vv[ci] = v;
        s += v;
        s2 = fmaf(v, v, s2);
    }
    __shared__ float S[16][17], S2[16][17];
    S[chunk][lpx] = s;
    S2[chunk][lpx] = s2;
    __syncthreads();
    float ts = 0.f, ts2 = 0.f;
#pragma unroll
    for (int k = 0; k < 16; ++k) { ts += S[k][lpx]; ts2 += S2[k][lpx]; }
    float mu = ts * (1.0f / DI);
    float var = ts2 * (1.0f / DI) - mu * mu;
    float inv = rsqrtf(var + 1e-5f);
#pragma unroll
    for (int ci = 0; ci < 24; ++ci) {
        int cch = chunk * 24 + ci;
        float v = (vv[ci] - mu) * inv;
        yb[(size_t)cch * HW] = fmaf(v, nw[cch], nb[cch]);
    }
}

// ---------------- K6: GRN per-channel sumsq -> Gx = sqrt(sum y^2) ----------------
// grid (384, 2), block 256.
__global__ __launch_bounds__(256) void k_grnsum(const float* __restrict__ y,
                                                float* __restrict__ gx) {
    int c = blockIdx.x, b = blockIdx.y;
    const float* yb = y + ((size_t)b * DI + c) * HW;
    float s = 0.f;
#pragma unroll 4
    for (int i = threadIdx.x; i < HW; i += 256) {
        float v = yb[i];
        s = fmaf(v, v, s);
    }
#pragma unroll
    for (int o = 32; o > 0; o >>= 1) s += __shfl_down(s, o);
    __shared__ float red[4];
    int wid = threadIdx.x >> 6;
    if ((threadIdx.x & 63) == 0) red[wid] = s;
    __syncthreads();
    if (threadIdx.x == 0) gx[b * DI + c] = sqrtf(red[0] + red[1] + red[2] + red[3]);
}

// ---------------- K7: GRN scale: sc = 1 + gamma * Gx/(mean+1e-6) ----------------
// grid 2, block 256. Each thread covers channels cidx and cidx+256 (DI=384).
__global__ __launch_bounds__(256) void k_grnscale(const float* __restrict__ gxv,
                                                  const float* __restrict__ gamma,
                                                  float* __restrict__ sc) {
    int b = blockIdx.x;
    const float* g = gxv + b * DI;
    int cidx = threadIdx.x;
    float gx0 = g[cidx];
    float gx1 = (cidx < DI - 256) ? g[cidx + 256] : 0.f;
    float s = gx0 + gx1;
#pragma unroll
    for (int o = 32; o > 0; o >>= 1) s += __shfl_down(s, o);
    __shared__ float red[4];
    __shared__ float meanv;
    int wid = threadIdx.x >> 6;
    if ((threadIdx.x & 63) == 0) red[wid] = s;
    __syncthreads();
    if (threadIdx.x == 0) meanv = (red[0] + red[1] + red[2] + red[3]) * (1.0f / DI);
    __syncthreads();
    float m = meanv + 1e-6f;
    sc[b * DI + cidx] = 1.0f + gamma[cidx] * (gx0 / m);
    if (cidx < DI - 256)
        sc[b * DI + cidx + 256] = 1.0f + gamma[cidx + 256] * (gx1 / m);
}

// ---------------- K8: out_proj GEMM fused with GRN scale/shift ----------------
// grid (16, 24, 2), block 256. Thread: 8 output channels for one pixel.
__global__ __launch_bounds__(256, 3) void k_outproj(const float* __restrict__ y,
                                                    const float* __restrict__ w,
                                                    const float* __restrict__ sc_all,
                                                    const float* __restrict__ beta,
                                                    float* __restrict__ out) {
    int og = blockIdx.y, b = blockIdx.z;
    int p = blockIdx.x * 256 + threadIdx.x;
    const float* wr = w + (size_t)og * 8 * DI;
    const float* scb = sc_all + b * DI;
    const float* yb = y + (size_t)b * DI * HW + p;
    float acc[8];
#pragma unroll
    for (int j = 0; j < 8; ++j) acc[j] = 0.f;
    for (int c = 0; c < DI; c += 4) {
        float v0 = fmaf(yb[(size_t)(c + 0) * HW], scb[c + 0], beta[c + 0]);
        float v1 = fmaf(yb[(size_t)(c + 1) * HW], scb[c + 1], beta[c + 1]);
        float v2 = fmaf(yb[(size_t)(c + 2) * HW], scb[c + 2], beta[c + 2]);
        float v3 = fmaf(yb[(size_t)(c + 3) * HW], scb[c + 3], beta[c + 3]);
#pragma unroll
        for (int j = 0; j < 8; ++j) {
            const float* wj = wr + j * DI + c;  // wave-uniform -> SGPR
            acc[j] = fmaf(wj[0], v0, fmaf(wj[1], v1, fmaf(wj[2], v2, fmaf(wj[3], v3, acc[j]))));
        }
    }
    float* ob = out + (size_t)b * DM * HW + (size_t)(og * 8) * HW + p;
#pragma unroll
    for (int j = 0; j < 8; ++j) ob[(size_t)j * HW] = acc[j];
}

extern "C" void kernel_launch(void* const* d_in, const int* in_sizes, int n_in,
                              void* d_out, int out_size, void* d_ws, size_t ws_size,
                              hipStream_t stream) {
    (void)in_sizes; (void)n_in; (void)out_size; (void)ws_size;
    const float* x          = (const float*)d_in[0];
    const float* in_proj_w  = (const float*)d_in[1];
    const float* dwconv_w   = (const float*)d_in[2];
    const float* dwconv_b   = (const float*)d_in[3];
    const float* x_down_w   = (const float*)d_in[4];
    const float* w_up_w     = (const float*)d_in[5];
    const float* l_up_w     = (const float*)d_in[6];
    const float* u_up_w     = (const float*)d_in[7];
    const float* d_up_w     = (const float*)d_in[8];
    const float* m_w        = (const float*)d_in[9];
    const float* grn_gamma  = (const float*)d_in[10];
    const float* grn_beta   = (const float*)d_in[11];
    const float* norm_w     = (const float*)d_in[12];
    const float* norm_b     = (const float*)d_in[13];
    const float* out_proj_w = (const float*)d_in[14];

    float* ws = (float*)d_ws;
    const size_t NBIG = (size_t)Bn * DI * HW;
    float* hpre = ws;                  // [B,DI,H,W], later reused as y
    float* hbuf = ws + NBIG;           // [B,DI,H,W] post-dwconv
    float* xpt  = ws + 2 * NBIG;       // [B,HW,DS]
    float* gx   = ws + 2 * NBIG + (size_t)Bn * HW * DS;
    float* sc   = gx + Bn * DI;
    float* y    = hpre;

    k_inproj<<<dim3(16, 24, 2), 256, 0, stream>>>(x, in_proj_w, hpre);
    k_dwconv<<<dim3(16, DI, Bn), 256, 0, stream>>>(hpre, dwconv_w, dwconv_b, hbuf);
    k_xdown<<<dim3(128), 256, 0, stream>>>(hbuf, x_down_w, xpt);
    k_scan<<<dim3(DI, Bn), 256, 0, stream>>>(hbuf, xpt, w_up_w, l_up_w, u_up_w,
                                             d_up_w, m_w, y);
    k_ln<<<dim3(512), 256, 0, stream>>>(y, norm_w, norm_b);
    k_grnsum<<<dim3(DI, Bn), 256, 0, stream>>>(y, gx);
    k_grnscale<<<dim3(Bn), 256, 0, stream>>>(gx, grn_gamma, sc);
    k_outproj<<<dim3(16, 24, 2), 256, 0, stream>>>(y, out_proj_w, sc, grn_beta,
                                                   (float*)d_out);
}

// Round 8
// 207.081 us; speedup vs baseline: 1.1708x; 1.0848x over previous
//
#include <hip/hip_runtime.h>
#include <math.h>

#define Bn 2
#define DM 192
#define DI 384
#define DS 16
#define HH 64
#define WW 64
#define HW 4096
#define ND 4

__device__ __forceinline__ float fastrcp(float x) { return __builtin_amdgcn_rcpf(x); }
__device__ __forceinline__ float fsig(float x) {
    return fastrcp(1.0f + __expf(-x));
}

// ---------------- K1: in_proj (1x1) + SiLU ----------------
// grid (16, 24, 2), block 256.
__global__ __launch_bounds__(256, 3) void k_inproj(const float* __restrict__ x,
                                                   const float* __restrict__ w,
                                                   float* __restrict__ hpre) {
    int og = blockIdx.y, b = blockIdx.z;
    int p = blockIdx.x * 256 + threadIdx.x;
    const float* wr = w + (size_t)og * 16 * DM;
    const float* xb = x + (size_t)b * DM * HW + p;
    float acc[16];
#pragma unroll
    for (int j = 0; j < 16; ++j) acc[j] = 0.f;
    for (int c = 0; c < DM; c += 4) {
        float x0 = xb[(size_t)(c + 0) * HW];
        float x1 = xb[(size_t)(c + 1) * HW];
        float x2 = xb[(size_t)(c + 2) * HW];
        float x3 = xb[(size_t)(c + 3) * HW];
#pragma unroll
        for (int j = 0; j < 16; ++j) {
            const float* wj = wr + j * DM + c;  // wave-uniform -> SGPR
            acc[j] = fmaf(wj[0], x0, fmaf(wj[1], x1, fmaf(wj[2], x2, fmaf(wj[3], x3, acc[j]))));
        }
    }
    float* hb = hpre + (size_t)b * DI * HW + (size_t)(og * 16) * HW + p;
#pragma unroll
    for (int j = 0; j < 16; ++j) {
        float v = acc[j];
        hb[(size_t)j * HW] = v * fastrcp(1.0f + __expf(-v));
    }
}

// ---------------- K2: depthwise 3x3 conv + bias ----------------
// grid (16, 384, 2), block 256.
__global__ __launch_bounds__(256) void k_dwconv(const float* __restrict__ hpre,
                                                const float* __restrict__ w,
                                                const float* __restrict__ bias,
                                                float* __restrict__ h) {
    int c = blockIdx.y, b = blockIdx.z;
    int p = blockIdx.x * 256 + threadIdx.x;
    int i = p >> 6, j = p & 63;
    const float* wp = w + c * 9;
    const float* src = hpre + ((size_t)b * DI + c) * HW;
    float acc = bias[c];
#pragma unroll
    for (int di = -1; di <= 1; ++di) {
        int ii = i + di;
        if (ii < 0 || ii >= HH) continue;
#pragma unroll
        for (int dj = -1; dj <= 1; ++dj) {
            int jj = j + dj;
            if (jj < 0 || jj >= WW) continue;
            acc = fmaf(wp[(di + 1) * 3 + (dj + 1)], src[ii * WW + jj], acc);
        }
    }
    h[((size_t)b * DI + c) * HW + p] = acc;
}

// ---------------- K3: x_down -> xp column-major [b][w][q][h] ----------------
// grid (128), block 256 = 4 waves. Wave = 96-channel slice; 64 pixels/block.
// Output layout chosen so k_scan's per-column loads are lane-contiguous.
__global__ __launch_bounds__(256) void k_xdown(const float* __restrict__ h,
                                               const float* __restrict__ w,
                                               float* __restrict__ xpt) {
    __shared__ float red[4][64][17];
    int tid = threadIdx.x;
    int px = tid & 63, cw = tid >> 6;
    int gp = blockIdx.x * 64 + px;
    int b = gp >> 12, p = gp & 4095;
    const float* hb = h + (size_t)b * DI * HW + p;
    int c0 = cw * 96;
    float a[16];
#pragma unroll
    for (int s = 0; s < 16; ++s) a[s] = 0.f;
    for (int cc = 0; cc < 96; cc += 4) {
        float h0 = hb[(size_t)(c0 + cc + 0) * HW];
        float h1 = hb[(size_t)(c0 + cc + 1) * HW];
        float h2 = hb[(size_t)(c0 + cc + 2) * HW];
        float h3 = hb[(size_t)(c0 + cc + 3) * HW];
#pragma unroll
        for (int s = 0; s < 16; ++s) {
            const float* ws = w + (size_t)s * DI + c0 + cc;  // wave-uniform -> s_load
            a[s] = fmaf(ws[0], h0, fmaf(ws[1], h1, fmaf(ws[2], h2, fmaf(ws[3], h3, a[s]))));
        }
    }
#pragma unroll
    for (int s = 0; s < 16; ++s) red[cw][px][s] = a[s];
    __syncthreads();
    int sg = tid >> 6;  // state quad
    float4 r;
    float* o = &r.x;
#pragma unroll
    for (int j = 0; j < 4; ++j) {
        int s = sg * 4 + j;
        o[j] = red[0][px][s] + red[1][px][s] + red[2][px][s] + red[3][px][s];
    }
    int hp = p >> 6, wp_ = p & 63;
    // float4 index: b*HW*4 + (w*4 + q)*64 + h
    reinterpret_cast<float4*>(xpt)[(size_t)b * (HW * 4) + (wp_ * 4 + sg) * 64 + hp] = r;
}

// 16-term dot of SGPR-resident weight array against 4 float4 quads.
#define DOT16(W, q0, q1, q2, q3) \
    fmaf(W[15], q3.w, fmaf(W[14], q3.z, fmaf(W[13], q3.y, fmaf(W[12], q3.x, \
    fmaf(W[11], q2.w, fmaf(W[10], q2.z, fmaf(W[9],  q2.y, fmaf(W[8],  q2.x, \
    fmaf(W[7],  q1.w, fmaf(W[6],  q1.z, fmaf(W[5],  q1.y, fmaf(W[4],  q1.x, \
    fmaf(W[3],  q0.w, fmaf(W[2],  q0.z, fmaf(W[1],  q0.y, W[0] * q0.x)))))))))))))))

// ---------------- K4: fused gate-recurrent scan, all 4 directions ----------------
// grid (384, 2), block 256 (4 waves = 4 directions, lane = h).
// Software-pipelined: bpermutes for column w are issued at the end of column
// w-1; the ~110-instr gate block for column w+1 executes while they fly.
// xp loads are lane-contiguous (1KB/instr) thanks to the [b][w][q][h] layout.
__global__ __launch_bounds__(256, 3) void k_scan(const float* __restrict__ h,
                                                 const float* __restrict__ xpt,
                                                 const float* __restrict__ wup,
                                                 const float* __restrict__ lup,
                                                 const float* __restrict__ uup,
                                                 const float* __restrict__ dup,
                                                 const float* __restrict__ mw,
                                                 float* __restrict__ y) {
    int c = blockIdx.x, b = blockIdx.y;
    int tid = threadIdx.x;
    int d = tid >> 6, hl = tid & 63;

    __shared__ float htile[64][65];
    __shared__ float acc[64][65];

    const float* hb = h + ((size_t)b * DI + c) * HW;
    for (int i = tid; i < HW; i += 256) {
        htile[i >> 6][i & 63] = hb[i];
        acc[i >> 6][i & 63] = 0.f;
    }

    int row = d * DI + c;
    const float* p1 = wup + (size_t)row * DS;
    const float* p2 = wup + (size_t)(4 * DI + row) * DS;
    const float* p3 = wup + (size_t)(8 * DI + row) * DS;
    const float* pL = lup + (size_t)row * DS;
    const float* pU = uup + (size_t)row * DS;
    const float* pD = dup + (size_t)row * DS;
    float md = mw[d];
    float w1[16], w2[16], w3[16], wL[16], wU[16], wD[16];
#pragma unroll
    for (int s = 0; s < 16; ++s) {
        w1[s] = p1[s]; w2[s] = p2[s]; w3[s] = p3[s];
        wL[s] = pL[s]; wU[s] = md * pU[s]; wD[s] = md * pD[s];
    }

    int xstep = (d & 1) ? 65 : 1;
    int xbase = (d & 1) ? hl : hl * 65;
    if (d & 2) { xbase += xstep * 63; xstep = -xstep; }
    const float* xptr = &htile[0][0] + xbase;

    int upA = ((hl - 1) & 63) << 2;
    int dnA = ((hl + 1) & 63) << 2;
    bool isTop = (hl == 0), isBot = (hl == 63);

    float* accp = &acc[hl][0];

    const float4* xg = reinterpret_cast<const float4*>(xpt) + (size_t)b * (HW * 4) + hl;

#define LOADQ(R0, R1, R2, R3, wcol) { \
    const float4* pp_ = xg + (size_t)(wcol) * 256; \
    R0 = pp_[0]; R1 = pp_[64]; R2 = pp_[128]; R3 = pp_[192]; }

#define PREP(g1S, g2S, g3S, invS, LS, US, DvS, XS, Q0, Q1, Q2, Q3) { \
    g1S = DOT16(w1, Q0, Q1, Q2, Q3); \
    g2S = DOT16(w2, Q0, Q1, Q2, Q3); \
    g3S = DOT16(w3, Q0, Q1, Q2, Q3); \
    LS  = DOT16(wL, Q0, Q1, Q2, Q3); \
    US  = DOT16(wU, Q0, Q1, Q2, Q3); \
    DvS = DOT16(wD, Q0, Q1, Q2, Q3); \
    g1S = fsig(g1S); g2S = fsig(g2S); g3S = fsig(g3S); \
    float ss_ = g2S + (isTop ? 0.f : g1S) + (isBot ? 0.f : g3S); \
    invS = fastrcp(fmaxf(ss_, 1e-7f)); \
    XS = *xptr; xptr += xstep; }

#define COMB(g1S, g2S, g3S, invS, LS, US, DvS, XS) { \
    float upv_ = isTop ? 0.f : __int_as_float(upr); \
    float dnv_ = isBot ? 0.f : __int_as_float(dnr); \
    float hnew_ = fmaf(LS, XS, invS * fmaf(g1S, upv_, fmaf(g2S, hprev, g3S * dnv_))); \
    atomicAdd(accp, fmaf(hnew_, US, XS * DvS)); accp += 1; \
    hprev = hnew_; \
    upr = __builtin_amdgcn_ds_bpermute(upA, __float_as_int(hprev)); \
    dnr = __builtin_amdgcn_ds_bpermute(dnA, __float_as_int(hprev)); }

    float4 A0, A1, A2, A3, B0, B1, B2, B3;
    float g1a, g2a, g3a, inva, La, Ua, Dva, Xa;
    float g1b, g2b, g3b, invb, Lb, Ub, Dvb, Xb;
    int upr, dnr;
    float hprev;

    LOADQ(A0, A1, A2, A3, 0);
    __syncthreads();  // htile + acc ready (PREP reads htile)

    PREP(g1a, g2a, g3a, inva, La, Ua, Dva, Xa, A0, A1, A2, A3);  // col 0
    LOADQ(A0, A1, A2, A3, 1);
    // combine col 0: hprev = 0, up = dn = 0 -> hnew = L*X
    hprev = La * Xa;
    atomicAdd(accp, fmaf(hprev, Ua, Xa * Dva)); accp += 1;
    upr = __builtin_amdgcn_ds_bpermute(upA, __float_as_int(hprev));
    dnr = __builtin_amdgcn_ds_bpermute(dnA, __float_as_int(hprev));
    LOADQ(B0, B1, B2, B3, 2);

    for (int w = 1; w < 63; w += 2) {
        PREP(g1b, g2b, g3b, invb, Lb, Ub, Dvb, Xb, A0, A1, A2, A3);  // col w
        LOADQ(A0, A1, A2, A3, w + 2);
        COMB(g1b, g2b, g3b, invb, Lb, Ub, Dvb, Xb);                   // col w
        PREP(g1a, g2a, g3a, inva, La, Ua, Dva, Xa, B0, B1, B2, B3);  // col w+1
        int wn = (w + 3 < 64) ? w + 3 : 63;
        LOADQ(B0, B1, B2, B3, wn);
        COMB(g1a, g2a, g3a, inva, La, Ua, Dva, Xa);                   // col w+1
    }
    // col 63 (A holds it)
    PREP(g1b, g2b, g3b, invb, Lb, Ub, Dvb, Xb, A0, A1, A2, A3);
    {
        float upv_ = isTop ? 0.f : __int_as_float(upr);
        float dnv_ = isBot ? 0.f : __int_as_float(dnr);
        float hnew_ = fmaf(Lb, Xb, invb * fmaf(g1b, upv_, fmaf(g2b, hprev, g3b * dnv_)));
        atomicAdd(accp, fmaf(hnew_, Ub, Xb * Dvb));
    }
#undef LOADQ
#undef PREP
#undef COMB

    __syncthreads();
    float* yb = y + ((size_t)b * DI + c) * HW;
    for (int i = tid; i < HW; i += 256) yb[i] = acc[i >> 6][i & 63];
}

// ---------------- K5: LayerNorm2d over channels, in-place, single pass ----------------
// grid (512), block 256. Block: 16 pixels x 16 channel-chunks (24 channels each).
__global__ __launch_bounds__(256) void k_ln(float* __restrict__ y,
                                            const float* __restrict__ nw,
                                            const float* __restrict__ nb) {
    int lpx = threadIdx.x & 15, chunk = threadIdx.x >> 4;
    int gp = blockIdx.x * 16 + lpx;  // global pixel 0..8191
    int b = gp >> 12, p = gp & 4095;
    float* yb = y + (size_t)b * DI * HW + p;

    float vv[24];
    float s = 0.f, s2 = 0.f;
#pragma unroll
    for (int ci = 0; ci < 24; ++ci) {
        float v = yb[(size_t)(chunk * 24 + ci) * HW];
        vv[ci] = v;
        s += v;
        s2 = fmaf(v, v, s2);
    }
    __shared__ float S[16][17], S2[16][17];
    S[chunk][lpx] = s;
    S2[chunk][lpx] = s2;
    __syncthreads();
    float ts = 0.f, ts2 = 0.f;
#pragma unroll
    for (int k = 0; k < 16; ++k) { ts += S[k][lpx]; ts2 += S2[k][lpx]; }
    float mu = ts * (1.0f / DI);
    float var = ts2 * (1.0f / DI) - mu * mu;
    float inv = rsqrtf(var + 1e-5f);
#pragma unroll
    for (int ci = 0; ci < 24; ++ci) {
        int cch = chunk * 24 + ci;
        float v = (vv[ci] - mu) * inv;
        yb[(size_t)cch * HW] = fmaf(v, nw[cch], nb[cch]);
    }
}

// ---------------- K6: GRN per-channel sumsq -> Gx = sqrt(sum y^2) ----------------
// grid (384, 2), block 256.
__global__ __launch_bounds__(256) void k_grnsum(const float* __restrict__ y,
                                                float* __restrict__ gx) {
    int c = blockIdx.x, b = blockIdx.y;
    const float* yb = y + ((size_t)b * DI + c) * HW;
    float s = 0.f;
#pragma unroll 4
    for (int i = threadIdx.x; i < HW; i += 256) {
        float v = yb[i];
        s = fmaf(v, v, s);
    }
#pragma unroll
    for (int o = 32; o > 0; o >>= 1) s += __shfl_down(s, o);
    __shared__ float red[4];
    int wid = threadIdx.x >> 6;
    if ((threadIdx.x & 63) == 0) red[wid] = s;
    __syncthreads();
    if (threadIdx.x == 0) gx[b * DI + c] = sqrtf(red[0] + red[1] + red[2] + red[3]);
}

// ---------------- K7: GRN scale: sc = 1 + gamma * Gx/(mean+1e-6) ----------------
// grid 2, block 256. Each thread covers channels cidx and cidx+256 (DI=384).
__global__ __launch_bounds__(256) void k_grnscale(const float* __restrict__ gxv,
                                                  const float* __restrict__ gamma,
                                                  float* __restrict__ sc) {
    int b = blockIdx.x;
    const float* g = gxv + b * DI;
    int cidx = threadIdx.x;
    float gx0 = g[cidx];
    float gx1 = (cidx < DI - 256) ? g[cidx + 256] : 0.f;
    float s = gx0 + gx1;
#pragma unroll
    for (int o = 32; o > 0; o >>= 1) s += __shfl_down(s, o);
    __shared__ float red[4];
    __shared__ float meanv;
    int wid = threadIdx.x >> 6;
    if ((threadIdx.x & 63) == 0) red[wid] = s;
    __syncthreads();
    if (threadIdx.x == 0) meanv = (red[0] + red[1] + red[2] + red[3]) * (1.0f / DI);
    __syncthreads();
    float m = meanv + 1e-6f;
    sc[b * DI + cidx] = 1.0f + gamma[cidx] * (gx0 / m);
    if (cidx < DI - 256)
        sc[b * DI + cidx + 256] = 1.0f + gamma[cidx + 256] * (gx1 / m);
}

// ---------------- K8: out_proj GEMM fused with GRN scale/shift ----------------
// grid (16, 24, 2), block 256. Thread: 8 output channels for one pixel.
__global__ __launch_bounds__(256, 3) void k_outproj(const float* __restrict__ y,
                                                    const float* __restrict__ w,
                                                    const float* __restrict__ sc_all,
                                                    const float* __restrict__ beta,
                                                    float* __restrict__ out) {
    int og = blockIdx.y, b = blockIdx.z;
    int p = blockIdx.x * 256 + threadIdx.x;
    const float* wr = w + (size_t)og * 8 * DI;
    const float* scb = sc_all + b * DI;
    const float* yb = y + (size_t)b * DI * HW + p;
    float acc[8];
#pragma unroll
    for (int j = 0; j < 8; ++j) acc[j] = 0.f;
    for (int c = 0; c < DI; c += 4) {
        float v0 = fmaf(yb[(size_t)(c + 0) * HW], scb[c + 0], beta[c + 0]);
        float v1 = fmaf(yb[(size_t)(c + 1) * HW], scb[c + 1], beta[c + 1]);
        float v2 = fmaf(yb[(size_t)(c + 2) * HW], scb[c + 2], beta[c + 2]);
        float v3 = fmaf(yb[(size_t)(c + 3) * HW], scb[c + 3], beta[c + 3]);
#pragma unroll
        for (int j = 0; j < 8; ++j) {
            const float* wj = wr + j * DI + c;  // wave-uniform -> SGPR
            acc[j] = fmaf(wj[0], v0, fmaf(wj[1], v1, fmaf(wj[2], v2, fmaf(wj[3], v3, acc[j]))));
        }
    }
    float* ob = out + (size_t)b * DM * HW + (size_t)(og * 8) * HW + p;
#pragma unroll
    for (int j = 0; j < 8; ++j) ob[(size_t)j * HW] = acc[j];
}

extern "C" void kernel_launch(void* const* d_in, const int* in_sizes, int n_in,
                              void* d_out, int out_size, void* d_ws, size_t ws_size,
                              hipStream_t stream) {
    (void)in_sizes; (void)n_in; (void)out_size; (void)ws_size;
    const float* x          = (const float*)d_in[0];
    const float* in_proj_w  = (const float*)d_in[1];
    const float* dwconv_w   = (const float*)d_in[2];
    const float* dwconv_b   = (const float*)d_in[3];
    const float* x_down_w   = (const float*)d_in[4];
    const float* w_up_w     = (const float*)d_in[5];
    const float* l_up_w     = (const float*)d_in[6];
    const float* u_up_w     = (const float*)d_in[7];
    const float* d_up_w     = (const float*)d_in[8];
    const float* m_w        = (const float*)d_in[9];
    const float* grn_gamma  = (const float*)d_in[10];
    const float* grn_beta   = (const float*)d_in[11];
    const float* norm_w     = (const float*)d_in[12];
    const float* norm_b     = (const float*)d_in[13];
    const float* out_proj_w = (const float*)d_in[14];

    float* ws = (float*)d_ws;
    const size_t NBIG = (size_t)Bn * DI * HW;
    float* hpre = ws;                  // [B,DI,H,W], later reused as y
    float* hbuf = ws + NBIG;           // [B,DI,H,W] post-dwconv
    float* xpt  = ws + 2 * NBIG;       // [B,W,4,64] column-major xp
    float* gx   = ws + 2 * NBIG + (size_t)Bn * HW * DS;
    float* sc   = gx + Bn * DI;
    float* y    = hpre;

    k_inproj<<<dim3(16, 24, 2), 256, 0, stream>>>(x, in_proj_w, hpre);
    k_dwconv<<<dim3(16, DI, Bn), 256, 0, stream>>>(hpre, dwconv_w, dwconv_b, hbuf);
    k_xdown<<<dim3(128), 256, 0, stream>>>(hbuf, x_down_w, xpt);
    k_scan<<<dim3(DI, Bn), 256, 0, stream>>>(hbuf, xpt, w_up_w, l_up_w, u_up_w,
                                             d_up_w, m_w, y);
    k_ln<<<dim3(512), 256, 0, stream>>>(y, norm_w, norm_b);
    k_grnsum<<<dim3(DI, Bn), 256, 0, stream>>>(y, gx);
    k_grnscale<<<dim3(Bn), 256, 0, stream>>>(gx, grn_gamma, sc);
    k_outproj<<<dim3(16, 24, 2), 256, 0, stream>>>(y, out_proj_w, sc, grn_beta,
                                                   (float*)d_out);
}